// Round 9
// baseline (125.634 us; speedup 1.0000x reference)
//
#include <hip/hip_runtime.h>

#define NF 64

// ws float offsets
#define OFF_NORMG   0          // 2048
#define OFF_NORMP   2048       // 2048
#define OFF_MAXG    8192       // 1
#define OFF_MAXP    8193       // 1
#define OFF_U       8194       // 128
#define OFF_HSUMG   8322       // 256
#define OFF_HSUMP   8578       // 256
#define OFF_NPG     9216       // 16384
#define OFF_NPP     25600      // 16384
#define OFF_HA_G    41984      // 131072
#define OFF_HA_P    173056
#define OFF_HB_G    304128
#define OFF_HB_P    435200
#define OFF_EG      566272
#define OFF_EP      697344
#define OFF_OBST    828416     // 1048576
#define OFF_AFRAG   2162688    // 2M ushorts (A frags, both sides)
#define OFF_HFA     3211264    // 1M ushorts = 524288 floats (h frags hi/lo x side), buffer A
#define OFF_HFB     3735552    // buffer B

typedef __attribute__((ext_vector_type(8))) short bf16x8;
typedef __attribute__((ext_vector_type(4))) float f32x4;

static __device__ __forceinline__ float wave_sum(float v) {
    for (int off = 32; off; off >>= 1) v += __shfl_down(v, off, 64);
    return v;
}
static __device__ __forceinline__ float wave_max(float v) {
    for (int off = 32; off; off >>= 1) v = fmaxf(v, __shfl_down(v, off, 64));
    return v;
}
static __device__ __forceinline__ unsigned short f2bf(float x) {   // RNE bf16
    unsigned u = __float_as_uint(x);
    return (unsigned short)((u + 0x7FFFu + ((u >> 16) & 1u)) >> 16);
}
static __device__ __forceinline__ float rdlane(float v, int k) {
    return __int_as_float(__builtin_amdgcn_readlane(__float_as_int(v), k));
}
// store h element into B-frag layout (hi/lo), frag buffer base fbase (float offset)
static __device__ __forceinline__ void store_hfrag(float* ws, int fbase, int sideS,
                                                   int lr, int f, float h) {
    int k = lr & 511, b = lr >> 9;
    int ft = f >> 4, ks = k >> 5;
    int lane2 = (f & 15) | (((k >> 3) & 3) << 4);
    int ii = k & 7;
    unsigned short hi = f2bf(h);
    float hif = __uint_as_float((unsigned)hi << 16);
    unsigned short lo = f2bf(h - hif);
    unsigned short* hf = (unsigned short*)(ws + fbase) + (size_t)sideS * 2 * 262144;
    size_t fidx = ((((size_t)b * 4 + ft) * 16 + ks) * 64 + lane2) * 8 + ii;
    hf[fidx] = hi;
    hf[262144 + fidx] = lo;
}

// ---------------- K1: transpose obs -> obsT, partial row/col counts; zero MAX ----------------
__global__ __launch_bounds__(256) void k_prep(const float* __restrict__ obs,
                                              float* __restrict__ ws) {
    __shared__ float tile[64][65];
    __shared__ float cc[4][64];
    int b = blockIdx.y, t = threadIdx.x;
    if (blockIdx.x == 0 && b == 0 && t == 0) { ws[OFF_MAXG] = 0.f; ws[OFF_MAXP] = 0.f; }
    int tg = blockIdx.x >> 3, tp = blockIdx.x & 7;
    int g0 = tg * 64, p0 = tp * 64;
    int c = t & 63, r0 = t >> 6;
    const float* src = obs + ((size_t)b * 512 + g0) * 512 + p0;
    float colcnt = 0.f;
#pragma unroll
    for (int i = 0; i < 16; ++i) {
        int r = r0 + 4 * i;
        float v = src[(size_t)r * 512 + c];
        tile[r][c] = v;
        float nz = (v != 0.f) ? 1.f : 0.f;
        colcnt += nz;
        nz = wave_sum(nz);
        if (c == 0) ws[OFF_NPG + tp * 2048 + b * 512 + g0 + r] = nz;
    }
    cc[r0][c] = colcnt;
    __syncthreads();
    if (r0 == 0)
        ws[OFF_NPP + tg * 2048 + b * 512 + p0 + c] =
            cc[0][c] + cc[1][c] + cc[2][c] + cc[3][c];
    float* dst = ws + OFF_OBST + ((size_t)b * 512 + p0) * 512 + g0;
#pragma unroll
    for (int i = 0; i < 16; ++i) {
        int pr = r0 + 4 * i;
        dst[(size_t)pr * 512 + c] = tile[c][pr];
    }
}

// ---------------- K2: norms + per-side max (16 atomics) + U (block 16) ----------------
__global__ __launch_bounds__(256) void k_norm(float* __restrict__ ws,
                                              const float* __restrict__ Wee_g,
                                              const float* __restrict__ Wef_g,
                                              const float* __restrict__ Wee_p,
                                              const float* __restrict__ Wef_p) {
    int bid = blockIdx.x;
    if (bid == 16) {
        int t = threadIdx.x;
        if (t < 128) {
            int side = t >> 6, f = t & 63;
            const float* Wee = side ? Wee_p : Wee_g;
            const float* Wef = side ? Wef_p : Wef_g;
            float u = 0.f;
#pragma unroll
            for (int e = 0; e < 63; ++e) u += fmaxf(Wee[e], 0.f) * Wef[e * 64 + f];
            ws[OFF_U + t] = u;
        }
        return;
    }
    __shared__ float red[4];
    int t = threadIdx.x, lane = t & 63, w = t >> 6;
    int idx = bid * 256 + t;            // 0..4095, side uniform per block (8 blocks/side)
    int side = idx >> 11, lr = idx & 2047;
    const float* part = ws + (side ? OFF_NPP : OFF_NPG) + lr;
    float s = 0.f;
#pragma unroll
    for (int j = 0; j < 8; ++j) s += part[j * 2048];
    ws[(side ? OFF_NORMP : OFF_NORMG) + lr] = s;
    float m = wave_max(s);
    if (lane == 0) red[w] = m;
    __syncthreads();
    if (t == 0) {
        float mm = fmaxf(fmaxf(red[0], red[1]), fmaxf(red[2], red[3]));
        atomicMax((int*)&ws[side ? OFF_MAXP : OFF_MAXG], __float_as_int(mm));
    }
}

// ---------------- K3: fused s-sums + init h/e + frag stores + A-frag pack ----------------
__global__ __launch_bounds__(256) void k_initpack(const float* __restrict__ obs,
                                                  float* __restrict__ ws,
                                                  const float* __restrict__ Wi_g,
                                                  const float* __restrict__ Wi_p,
                                                  const float* __restrict__ Wef_g,
                                                  const float* __restrict__ Wef_p) {
    __shared__ float s_l[16];
    int bid = blockIdx.x, side = bid >> 7, rt = bid & 127;
    int lr0 = rt * 16, b = lr0 >> 9;
    int t = threadIdx.x, lane = t & 63, w = t >> 6;
    const float* base = side ? (ws + OFF_OBST) : obs;
    const float* normopp = ws + (side ? OFF_NORMG : OFF_NORMP) + b * 512;
    // s for 16 rows (4 per wave)
    for (int q = 0; q < 4; ++q) {
        int lr = lr0 + w * 4 + q;
        const float* arow = base + (size_t)lr * 512;
        float sv = 0.f;
#pragma unroll
        for (int j = 0; j < 8; ++j) {
            float v = arow[lane + 64 * j];
            if (v != 0.f) sv += normopp[lane + 64 * j];
        }
        sv = wave_sum(sv) * (1.f / 512.f);
        if (lane == 0) s_l[w * 4 + q] = sv;
    }
    __syncthreads();
    // init h, e: 4 elements per thread
    float maxnf = fmaxf(ws[side ? OFF_MAXP : OFF_MAXG], 1.f);
    const float* Wi = side ? Wi_p : Wi_g;
    const float* Wef = side ? Wef_p : Wef_g;
#pragma unroll
    for (int q = 0; q < 4; ++q) {
        int idx = t + 256 * q;          // 0..1023
        int r = idx >> 6, ff = idx & 63;
        int lr = lr0 + r;
        float norm = ws[(side ? OFF_NORMP : OFF_NORMG) + lr];
        float nf1 = norm > 0.f ? norm : 1.f;
        float h = fmaxf(norm * (1.f / 512.f) * Wi[ff], 0.f);
        ws[(side ? OFF_HA_P : OFF_HA_G) + (size_t)lr * 64 + ff] = h;
        store_hfrag(ws, OFF_HFA, side, lr, ff, h);
        float A = s_l[r] / nf1;
        float C = norm / maxnf;
        float U = ws[OFF_U + side * 64 + ff];
        float e = fmaxf(A * U + C * Wef[63 * 64 + ff], 0.f);
        ws[(side ? OFF_EP : OFF_EG) + (size_t)lr * 64 + ff] = e;
    }
    // pack A-frags (16 ks, 4 per wave) — verified layout (R8 pass)
    unsigned short* dst = (unsigned short*)(ws + OFF_AFRAG) + (size_t)side * 1048576;
    int row = rt * 16 + (lane & 15);
    int kbase = (lane >> 4) << 3;
#pragma unroll
    for (int q = 0; q < 4; ++q) {
        int ks = w * 4 + q;
        const float* s = base + (size_t)row * 512 + ks * 32 + kbase;
        bf16x8 o;
#pragma unroll
        for (int i = 0; i < 8; ++i) o[i] = (short)f2bf(s[i]);
        *(bf16x8*)(dst + ((size_t)(rt * 16 + ks) * 64 + lane) * 8) = o;
    }
}

// ---------------- K4: fused layer (MFMA agg + readlane MLP). 512 blocks x 512 thr ----------------
// Block = 8 rows of one side (half of a 16-row MFMA tile). 8 waves:
// agg: (ft 0..3) x (hi/lo); MLP: 1 row/wave, W coalesced vloads, x broadcast via readlane.
__global__ __launch_bounds__(512, 4) void k_layer(float* __restrict__ ws,
        const float* __restrict__ Wmsg_g, const float* __restrict__ Wupd_g,
        const float* __restrict__ Wmsg_p, const float* __restrict__ Wupd_p,
        int layer, int hin_g, int hin_p, int hout_g, int hout_p, int fin, int fout) {
    __shared__ float comb[16][64];
    __shared__ float aggx[8][68];
    int bid = blockIdx.x, side = bid >> 8, tile8 = bid & 255;
    int rt = tile8 >> 1, half = tile8 & 1;
    int lr0 = tile8 * 8;
    int b = rt >> 5;
    int t = threadIdx.x, lane = t & 63, w = t >> 6;   // 8 waves
    int ft = w & 3, part = w >> 2;

    // ---- agg via MFMA over 16-row tile rt ----
    const unsigned short* af = (const unsigned short*)(ws + OFF_AFRAG) + (size_t)side * 1048576;
    const unsigned short* hf = (const unsigned short*)(ws + fin)
                               + (size_t)(1 - side) * 2 * 262144 + (size_t)part * 262144;
    f32x4 acc = {0.f, 0.f, 0.f, 0.f};
#pragma unroll
    for (int ks = 0; ks < 16; ++ks) {
        bf16x8 a = *(const bf16x8*)(af + ((size_t)(rt * 16 + ks) * 64 + lane) * 8);
        bf16x8 bb = *(const bf16x8*)(hf + ((((size_t)b * 4 + ft) * 16 + ks) * 64 + lane) * 8);
        acc = __builtin_amdgcn_mfma_f32_16x16x32_bf16(a, bb, acc, 0, 0, 0);
    }
    int r16q = (lane >> 4) << 2;        // first of this lane's 4 C rows
    int f = ft * 16 + (lane & 15);
    if (part == 1) {
#pragma unroll
        for (int j = 0; j < 4; ++j) comb[r16q + j][f] = acc[j];
    }
    __syncthreads();
    if (part == 0 && (r16q >> 3) == half) {
        const float* nrm = ws + (side ? OFF_NORMP : OFF_NORMG) + rt * 16;
#pragma unroll
        for (int j = 0; j < 4; ++j) {
            int r16 = r16q + j;
            float v = (acc[j] + comb[r16][f]) / fmaxf(nrm[r16], 1.f);
            aggx[r16 - half * 8][f] = v;
        }
    }
    __syncthreads();

    // ---- MLP: wave w -> row lr0 + w ----
    int lr = lr0 + w;
    const float* Wm = (side ? Wmsg_p : Wmsg_g) + layer * 8192;
    const float* Wu = (side ? Wupd_p : Wupd_g) + layer * 8192;
    float xa = aggx[w][lane];
    float xe = ws[(side ? OFF_EP : OFF_EG) + (size_t)lr * 64 + lane];
    float xh = ws[(side ? hin_p : hin_g) + (size_t)lr * 64 + lane];

    float a0 = 0.f, a1 = 0.f;
#pragma unroll 8
    for (int k = 0; k < 64; k += 2) {
        a0 = fmaf(rdlane(xa, k),     Wm[k * 64 + lane],       a0);
        a1 = fmaf(rdlane(xa, k + 1), Wm[(k + 1) * 64 + lane], a1);
    }
#pragma unroll 8
    for (int k = 0; k < 64; k += 2) {
        a0 = fmaf(rdlane(xe, k),     Wm[(64 + k) * 64 + lane], a0);
        a1 = fmaf(rdlane(xe, k + 1), Wm[(65 + k) * 64 + lane], a1);
    }
    float m = fmaxf(a0 + a1, 0.f);

    float b0 = 0.f, b1 = 0.f;
#pragma unroll 8
    for (int k = 0; k < 64; k += 2) {
        b0 = fmaf(rdlane(xh, k),     Wu[k * 64 + lane],       b0);
        b1 = fmaf(rdlane(xh, k + 1), Wu[(k + 1) * 64 + lane], b1);
    }
#pragma unroll 8
    for (int k = 0; k < 64; k += 2) {
        b0 = fmaf(rdlane(m, k),      Wu[(64 + k) * 64 + lane], b0);
        b1 = fmaf(rdlane(m, k + 1),  Wu[(65 + k) * 64 + lane], b1);
    }
    float hn = fmaxf(b0 + b1, 0.f);
    ws[(side ? hout_p : hout_g) + (size_t)lr * 64 + lane] = hn;
    store_hfrag(ws, fout, side, lr, lane, hn);
}

// ---------------- K5: column sums of final h ----------------
__global__ __launch_bounds__(256) void k_hsum(float* __restrict__ ws) {
    __shared__ float red[4][NF];
    int bid = blockIdx.x, side = bid >> 2, b = bid & 3;
    int t = threadIdx.x, f = t & 63, w = t >> 6;
    const float* h = ws + (side ? OFF_HB_P : OFF_HB_G) + (size_t)b * 32768;
    float s = 0.f;
    for (int r = w; r < 512; r += 4) s += h[(size_t)r * 64 + f];
    red[w][f] = s;
    __syncthreads();
    if (w == 0)
        ws[(side ? OFF_HSUMP : OFF_HSUMG) + b * 64 + f] =
            red[0][f] + red[1][f] + red[2][f] + red[3][f];
}

// ---------------- K6: fused pool + readout. 8 blocks x 256 ----------------
__global__ __launch_bounds__(256) void k_out(const float* __restrict__ Wpg,
                                             const float* __restrict__ Wpp,
                                             const float* __restrict__ Wro,
                                             const float* __restrict__ bro,
                                             const float* __restrict__ ws,
                                             float* __restrict__ out) {
    __shared__ float hp[128];
    __shared__ float c1s;
    int bid = blockIdx.x;
    int row0 = bid * 256, b = row0 >> 9;
    int t = threadIdx.x;
    if (t < 128) {
        int sd = t >> 6, k = t & 63;
        hp[t] = ws[(sd ? OFF_HSUMP : OFF_HSUMG) + b * 64 + k];
    }
    __syncthreads();
    if (t < 64) {
        float vg = 0.f, vp = 0.f;
#pragma unroll 4
        for (int k = 0; k < 64; ++k) {
            vg += (hp[k] * (1.f / 512.f)) * Wpg[k * 64 + t];
            vp += (hp[64 + k] * (1.f / 512.f)) * Wpp[k * 64 + t];
        }
        float hv = fmaxf(vg + vp, 0.f);
        float c = wave_sum(hv * Wro[t]);
        if (t == 0) c1s = c + bro[0];
    }
    __syncthreads();
    int idx = row0 + t;
    const float4* hrow = (const float4*)(ws + OFF_HB_G + (size_t)idx * 64);
    float s = 0.f;
#pragma unroll
    for (int k4 = 0; k4 < 16; ++k4) {
        float4 h4 = hrow[k4];
        s += h4.x * Wro[64 + k4 * 4 + 0];
        s += h4.y * Wro[64 + k4 * 4 + 1];
        s += h4.z * Wro[64 + k4 * 4 + 2];
        s += h4.w * Wro[64 + k4 * 4 + 3];
    }
    out[idx] = c1s + s;
}

extern "C" void kernel_launch(void* const* d_in, const int* in_sizes, int n_in,
                              void* d_out, int out_size, void* d_ws, size_t ws_size,
                              hipStream_t stream) {
    const float* obs   = (const float*)d_in[0];
    const float* Wi_g  = (const float*)d_in[1];
    const float* Wi_p  = (const float*)d_in[2];
    const float* Wee_g = (const float*)d_in[3];
    const float* Wef_g = (const float*)d_in[4];
    const float* Wee_p = (const float*)d_in[5];
    const float* Wef_p = (const float*)d_in[6];
    const float* Wm_g  = (const float*)d_in[7];
    const float* Wu_g  = (const float*)d_in[8];
    const float* Wm_p  = (const float*)d_in[9];
    const float* Wu_p  = (const float*)d_in[10];
    const float* Wpg   = (const float*)d_in[11];
    const float* Wpp   = (const float*)d_in[12];
    const float* Wro   = (const float*)d_in[13];
    const float* bro   = (const float*)d_in[14];
    float* ws  = (float*)d_ws;
    float* out = (float*)d_out;

    k_prep<<<dim3(64, 4), 256, 0, stream>>>(obs, ws);
    k_norm<<<17, 256, 0, stream>>>(ws, Wee_g, Wef_g, Wee_p, Wef_p);
    k_initpack<<<256, 256, 0, stream>>>(obs, ws, Wi_g, Wi_p, Wef_g, Wef_p);

    k_layer<<<512, 512, 0, stream>>>(ws, Wm_g, Wu_g, Wm_p, Wu_p, 0,
                                     OFF_HA_G, OFF_HA_P, OFF_HB_G, OFF_HB_P,
                                     OFF_HFA, OFF_HFB);
    k_layer<<<512, 512, 0, stream>>>(ws, Wm_g, Wu_g, Wm_p, Wu_p, 1,
                                     OFF_HB_G, OFF_HB_P, OFF_HA_G, OFF_HA_P,
                                     OFF_HFB, OFF_HFA);
    k_layer<<<512, 512, 0, stream>>>(ws, Wm_g, Wu_g, Wm_p, Wu_p, 2,
                                     OFF_HA_G, OFF_HA_P, OFF_HB_G, OFF_HB_P,
                                     OFF_HFA, OFF_HFB);

    k_hsum<<<8, 256, 0, stream>>>(ws);
    k_out<<<8, 256, 0, stream>>>(Wpg, Wpp, Wro, bro, ws, out);
}

// Round 10
// 78.333 us; speedup vs baseline: 1.6038x; 1.6038x over previous
//
#include <hip/hip_runtime.h>

#define NF 64

// ws float offsets
#define OFF_NORMG   0          // 2048
#define OFF_NORMP   2048       // 2048
#define OFF_MAXG    8192       // 1
#define OFF_MAXP    8193       // 1
#define OFF_U       8194       // 128
#define OFF_HSUMG   8322       // 256 (unused now)
#define OFF_HSUMP   8578       // 256 (unused now)
#define OFF_NPG     9216       // 16384
#define OFF_NPP     25600      // 16384
#define OFF_HA_G    41984      // 131072
#define OFF_HA_P    173056
#define OFF_HB_G    304128
#define OFF_HB_P    435200
#define OFF_EG      566272
#define OFF_EP      697344
#define OFF_OBST    828416     // 1048576
#define OFF_AFRAG   2162688    // 2M ushorts (A frags, both sides)
#define OFF_HFA     3211264    // 1M ushorts (h frags hi/lo x side), buffer A
#define OFF_HFB     3735552    // buffer B
#define OFF_WF      4259840    // 196608 ushorts: W frags hi/lo, 12 matrices
#define OFF_HPART   4358144    // 64*64 floats

typedef __attribute__((ext_vector_type(8))) short bf16x8;
typedef __attribute__((ext_vector_type(4))) float f32x4;

static __device__ __forceinline__ float wave_sum(float v) {
    for (int off = 32; off; off >>= 1) v += __shfl_down(v, off, 64);
    return v;
}
static __device__ __forceinline__ float wave_max(float v) {
    for (int off = 32; off; off >>= 1) v = fmaxf(v, __shfl_down(v, off, 64));
    return v;
}
static __device__ __forceinline__ unsigned short f2bf(float x) {   // RNE bf16
    unsigned u = __float_as_uint(x);
    return (unsigned short)((u + 0x7FFFu + ((u >> 16) & 1u)) >> 16);
}
// store h element into B-frag layout (hi/lo), frag buffer base fbase (float offset)
static __device__ __forceinline__ void store_hfrag(float* ws, int fbase, int sideS,
                                                   int lr, int f, float h) {
    int k = lr & 511, b = lr >> 9;
    int ft = f >> 4, ks = k >> 5;
    int lane2 = (f & 15) | (((k >> 3) & 3) << 4);
    int ii = k & 7;
    unsigned short hi = f2bf(h);
    float hif = __uint_as_float((unsigned)hi << 16);
    unsigned short lo = f2bf(h - hif);
    unsigned short* hf = (unsigned short*)(ws + fbase) + (size_t)sideS * 2 * 262144;
    size_t fidx = ((((size_t)b * 4 + ft) * 16 + ks) * 64 + lane2) * 8 + ii;
    hf[fidx] = hi;
    hf[262144 + fidx] = lo;
}

// ---------------- K1: transpose obs -> obsT, partial row/col counts; zero MAX ----------------
__global__ __launch_bounds__(256) void k_prep(const float* __restrict__ obs,
                                              float* __restrict__ ws) {
    __shared__ float tile[64][65];
    __shared__ float cc[4][64];
    int b = blockIdx.y, t = threadIdx.x;
    if (blockIdx.x == 0 && b == 0 && t == 0) { ws[OFF_MAXG] = 0.f; ws[OFF_MAXP] = 0.f; }
    int tg = blockIdx.x >> 3, tp = blockIdx.x & 7;
    int g0 = tg * 64, p0 = tp * 64;
    int c = t & 63, r0 = t >> 6;
    const float* src = obs + ((size_t)b * 512 + g0) * 512 + p0;
    float colcnt = 0.f;
#pragma unroll
    for (int i = 0; i < 16; ++i) {
        int r = r0 + 4 * i;
        float v = src[(size_t)r * 512 + c];
        tile[r][c] = v;
        float nz = (v != 0.f) ? 1.f : 0.f;
        colcnt += nz;
        nz = wave_sum(nz);
        if (c == 0) ws[OFF_NPG + tp * 2048 + b * 512 + g0 + r] = nz;
    }
    cc[r0][c] = colcnt;
    __syncthreads();
    if (r0 == 0)
        ws[OFF_NPP + tg * 2048 + b * 512 + p0 + c] =
            cc[0][c] + cc[1][c] + cc[2][c] + cc[3][c];
    float* dst = ws + OFF_OBST + ((size_t)b * 512 + p0) * 512 + g0;
#pragma unroll
    for (int i = 0; i < 16; ++i) {
        int pr = r0 + 4 * i;
        dst[(size_t)pr * 512 + c] = tile[c][pr];
    }
}

// ---------------- K1c: pack 12 weight matrices into bf16 hi/lo B-frags ----------------
// B-frag map (R8-verified): lane holds B[ks2*32 + ((lane>>4)&3)*8 + i][ft*16 + (lane&15)]
__global__ __launch_bounds__(256) void k_wpack(float* __restrict__ ws,
        const float* __restrict__ Wm_g, const float* __restrict__ Wu_g,
        const float* __restrict__ Wm_p, const float* __restrict__ Wu_p) {
    int bid = blockIdx.x;              // 48 = 12 mats x 4 ks2
    int mat = bid >> 2, ks2 = bid & 3;
    int side = mat / 6, m = (mat / 3) & 1, layer = mat % 3;
    const float* W = (side ? (m ? Wu_p : Wm_p) : (m ? Wu_g : Wm_g)) + layer * 8192;
    int t = threadIdx.x, ftq = t >> 6, lane = t & 63;
    int f = ftq * 16 + (lane & 15);
    int kbase = ks2 * 32 + ((lane >> 4) & 3) * 8;
    bf16x8 oh, ol;
#pragma unroll
    for (int i = 0; i < 8; ++i) {
        float v = W[(kbase + i) * 64 + f];
        unsigned short hi = f2bf(v);
        oh[i] = (short)hi;
        ol[i] = (short)f2bf(v - __uint_as_float((unsigned)hi << 16));
    }
    unsigned short* WF = (unsigned short*)(ws + OFF_WF);
    *(bf16x8*)(WF + (((size_t)(mat * 2 + 0) * 4 + ks2) * 4 + ftq) * 512 + lane * 8) = oh;
    *(bf16x8*)(WF + (((size_t)(mat * 2 + 1) * 4 + ks2) * 4 + ftq) * 512 + lane * 8) = ol;
}

// ---------------- K2: norms + per-side max + U (block 16) ----------------
__global__ __launch_bounds__(256) void k_norm(float* __restrict__ ws,
                                              const float* __restrict__ Wee_g,
                                              const float* __restrict__ Wef_g,
                                              const float* __restrict__ Wee_p,
                                              const float* __restrict__ Wef_p) {
    int bid = blockIdx.x;
    if (bid == 16) {
        int t = threadIdx.x;
        if (t < 128) {
            int side = t >> 6, f = t & 63;
            const float* Wee = side ? Wee_p : Wee_g;
            const float* Wef = side ? Wef_p : Wef_g;
            float u = 0.f;
#pragma unroll
            for (int e = 0; e < 63; ++e) u += fmaxf(Wee[e], 0.f) * Wef[e * 64 + f];
            ws[OFF_U + t] = u;
        }
        return;
    }
    __shared__ float red[4];
    int t = threadIdx.x, lane = t & 63, w = t >> 6;
    int idx = bid * 256 + t;            // side uniform per block
    int side = idx >> 11, lr = idx & 2047;
    const float* part = ws + (side ? OFF_NPP : OFF_NPG) + lr;
    float s = 0.f;
#pragma unroll
    for (int j = 0; j < 8; ++j) s += part[j * 2048];
    ws[(side ? OFF_NORMP : OFF_NORMG) + lr] = s;
    float m = wave_max(s);
    if (lane == 0) red[w] = m;
    __syncthreads();
    if (t == 0) {
        float mm = fmaxf(fmaxf(red[0], red[1]), fmaxf(red[2], red[3]));
        atomicMax((int*)&ws[side ? OFF_MAXP : OFF_MAXG], __float_as_int(mm));
    }
}

// ---------------- K3: fused s-sums + init h/e + frag stores + A-frag pack ----------------
__global__ __launch_bounds__(256) void k_initpack(const float* __restrict__ obs,
                                                  float* __restrict__ ws,
                                                  const float* __restrict__ Wi_g,
                                                  const float* __restrict__ Wi_p,
                                                  const float* __restrict__ Wef_g,
                                                  const float* __restrict__ Wef_p) {
    __shared__ float s_l[16];
    int bid = blockIdx.x, side = bid >> 7, rt = bid & 127;
    int lr0 = rt * 16, b = lr0 >> 9;
    int t = threadIdx.x, lane = t & 63, w = t >> 6;
    const float* base = side ? (ws + OFF_OBST) : obs;
    const float* normopp = ws + (side ? OFF_NORMG : OFF_NORMP) + b * 512;
    for (int q = 0; q < 4; ++q) {
        int lr = lr0 + w * 4 + q;
        const float* arow = base + (size_t)lr * 512;
        float sv = 0.f;
#pragma unroll
        for (int j = 0; j < 8; ++j) {
            float v = arow[lane + 64 * j];
            if (v != 0.f) sv += normopp[lane + 64 * j];
        }
        sv = wave_sum(sv) * (1.f / 512.f);
        if (lane == 0) s_l[w * 4 + q] = sv;
    }
    __syncthreads();
    float maxnf = fmaxf(ws[side ? OFF_MAXP : OFF_MAXG], 1.f);
    const float* Wi = side ? Wi_p : Wi_g;
    const float* Wef = side ? Wef_p : Wef_g;
#pragma unroll
    for (int q = 0; q < 4; ++q) {
        int idx = t + 256 * q;
        int r = idx >> 6, ff = idx & 63;
        int lr = lr0 + r;
        float norm = ws[(side ? OFF_NORMP : OFF_NORMG) + lr];
        float nf1 = norm > 0.f ? norm : 1.f;
        float h = fmaxf(norm * (1.f / 512.f) * Wi[ff], 0.f);
        ws[(side ? OFF_HA_P : OFF_HA_G) + (size_t)lr * 64 + ff] = h;
        store_hfrag(ws, OFF_HFA, side, lr, ff, h);
        float A = s_l[r] / nf1;
        float C = norm / maxnf;
        float U = ws[OFF_U + side * 64 + ff];
        float e = fmaxf(A * U + C * Wef[63 * 64 + ff], 0.f);
        ws[(side ? OFF_EP : OFF_EG) + (size_t)lr * 64 + ff] = e;
    }
    unsigned short* dst = (unsigned short*)(ws + OFF_AFRAG) + (size_t)side * 1048576;
    int row = rt * 16 + (lane & 15);
    int kbase = (lane >> 4) << 3;
#pragma unroll
    for (int q = 0; q < 4; ++q) {
        int ks = w * 4 + q;
        const float* s = base + (size_t)row * 512 + ks * 32 + kbase;
        bf16x8 o;
#pragma unroll
        for (int i = 0; i < 8; ++i) o[i] = (short)f2bf(s[i]);
        *(bf16x8*)(dst + ((size_t)(rt * 16 + ks) * 64 + lane) * 8) = o;
    }
}

// ---------------- K4: full-MFMA layer. 256 blocks x 256 threads ----------------
// Block = 16-row tile of one side. Wave ft owns f-columns ft*16..+15 everywhere.
// agg (K=512, hi/lo) -> LDS -> msg GEMM (hi/lo x hi/lo MFMA) -> LDS -> upd GEMM.
__global__ __launch_bounds__(256) void k_layer(float* __restrict__ ws, int layer,
        int hin_g, int hin_p, int hout_g, int hout_p, int fin, int fout) {
    __shared__ float xe[16][68], xh[16][68], xa[16][68], xm[16][68];
    int bid = blockIdx.x, side = bid >> 7, rt = bid & 127;
    int lr0 = rt * 16, b = rt >> 5;
    int t = threadIdx.x, lane = t & 63;
    int ft = __builtin_amdgcn_readfirstlane(t >> 6);

    {   // stage e and h_self tiles (coalesced float4)
        int r = t >> 4, c4 = (t & 15) * 4;
        *(float4*)&xe[r][c4] = *(const float4*)(ws + (side ? OFF_EP : OFF_EG)
                                                + (size_t)(lr0 + r) * 64 + c4);
        *(float4*)&xh[r][c4] = *(const float4*)(ws + (side ? hin_p : hin_g)
                                                + (size_t)(lr0 + r) * 64 + c4);
    }

    // ---- agg via MFMA (R8-verified layout) ----
    const unsigned short* af = (const unsigned short*)(ws + OFF_AFRAG) + (size_t)side * 1048576;
    const unsigned short* hfh = (const unsigned short*)(ws + fin)
                                + (size_t)(1 - side) * 2 * 262144;
    const unsigned short* hfl = hfh + 262144;
    f32x4 acc = {0.f, 0.f, 0.f, 0.f};
#pragma unroll
    for (int ks = 0; ks < 16; ++ks) {
        bf16x8 a = *(const bf16x8*)(af + ((size_t)(rt * 16 + ks) * 64 + lane) * 8);
        size_t bi = ((((size_t)b * 4 + ft) * 16 + ks) * 64 + lane) * 8;
        bf16x8 bh = *(const bf16x8*)(hfh + bi);
        bf16x8 bl = *(const bf16x8*)(hfl + bi);
        acc = __builtin_amdgcn_mfma_f32_16x16x32_bf16(a, bh, acc, 0, 0, 0);
        acc = __builtin_amdgcn_mfma_f32_16x16x32_bf16(a, bl, acc, 0, 0, 0);
    }
    {   // normalize, write x_agg tile
        int c = lane & 15, rq = (lane >> 4) * 4, f = ft * 16 + c;
#pragma unroll
        for (int j = 0; j < 4; ++j) {
            float nrm = ws[(side ? OFF_NORMP : OFF_NORMG) + lr0 + rq + j];
            xa[rq + j][f] = acc[j] / fmaxf(nrm, 1.f);
        }
    }
    __syncthreads();

    const unsigned short* WF = (const unsigned short*)(ws + OFF_WF);
    int mat_msg = (side * 2 + 0) * 3 + layer;
    int mat_upd = (side * 2 + 1) * 3 + layer;
    int ar = lane & 15, koff = ((lane >> 4) & 3) * 8;

    // ---- msg GEMM: [agg | e] @ Wm ----
    f32x4 mc = {0.f, 0.f, 0.f, 0.f};
#pragma unroll
    for (int ks2 = 0; ks2 < 4; ++ks2) {
        const float* src = (ks2 < 2) ? &xa[ar][ks2 * 32 + koff]
                                     : &xe[ar][(ks2 - 2) * 32 + koff];
        float4 lo4 = *(const float4*)src;
        float4 hi4 = *(const float4*)(src + 4);
        float xv0 = lo4.x, xv1 = lo4.y, xv2 = lo4.z, xv3 = lo4.w;
        float xv4 = hi4.x, xv5 = hi4.y, xv6 = hi4.z, xv7 = hi4.w;
        bf16x8 xhf, xlf;
        {
            float xv[8] = {xv0, xv1, xv2, xv3, xv4, xv5, xv6, xv7};
#pragma unroll
            for (int i = 0; i < 8; ++i) {
                unsigned short hh = f2bf(xv[i]);
                xhf[i] = (short)hh;
                xlf[i] = (short)f2bf(xv[i] - __uint_as_float((unsigned)hh << 16));
            }
        }
        bf16x8 wh = *(const bf16x8*)(WF + (((size_t)(mat_msg * 2 + 0) * 4 + ks2) * 4 + ft) * 512 + lane * 8);
        bf16x8 wl = *(const bf16x8*)(WF + (((size_t)(mat_msg * 2 + 1) * 4 + ks2) * 4 + ft) * 512 + lane * 8);
        mc = __builtin_amdgcn_mfma_f32_16x16x32_bf16(xhf, wh, mc, 0, 0, 0);
        mc = __builtin_amdgcn_mfma_f32_16x16x32_bf16(xlf, wh, mc, 0, 0, 0);
        mc = __builtin_amdgcn_mfma_f32_16x16x32_bf16(xhf, wl, mc, 0, 0, 0);
    }
    {   // relu -> x_m tile
        int c = lane & 15, rq = (lane >> 4) * 4, f = ft * 16 + c;
#pragma unroll
        for (int j = 0; j < 4; ++j) xm[rq + j][f] = fmaxf(mc[j], 0.f);
    }
    __syncthreads();

    // ---- upd GEMM: [h_self | m] @ Wu ----
    f32x4 uc = {0.f, 0.f, 0.f, 0.f};
#pragma unroll
    for (int ks2 = 0; ks2 < 4; ++ks2) {
        const float* src = (ks2 < 2) ? &xh[ar][ks2 * 32 + koff]
                                     : &xm[ar][(ks2 - 2) * 32 + koff];
        float4 lo4 = *(const float4*)src;
        float4 hi4 = *(const float4*)(src + 4);
        bf16x8 xhf, xlf;
        {
            float xv[8] = {lo4.x, lo4.y, lo4.z, lo4.w, hi4.x, hi4.y, hi4.z, hi4.w};
#pragma unroll
            for (int i = 0; i < 8; ++i) {
                unsigned short hh = f2bf(xv[i]);
                xhf[i] = (short)hh;
                xlf[i] = (short)f2bf(xv[i] - __uint_as_float((unsigned)hh << 16));
            }
        }
        bf16x8 wh = *(const bf16x8*)(WF + (((size_t)(mat_upd * 2 + 0) * 4 + ks2) * 4 + ft) * 512 + lane * 8);
        bf16x8 wl = *(const bf16x8*)(WF + (((size_t)(mat_upd * 2 + 1) * 4 + ks2) * 4 + ft) * 512 + lane * 8);
        uc = __builtin_amdgcn_mfma_f32_16x16x32_bf16(xhf, wh, uc, 0, 0, 0);
        uc = __builtin_amdgcn_mfma_f32_16x16x32_bf16(xlf, wh, uc, 0, 0, 0);
        uc = __builtin_amdgcn_mfma_f32_16x16x32_bf16(xhf, wl, uc, 0, 0, 0);
    }
    {   // relu -> hout f32 + hfrag hi/lo
        int c = lane & 15, rq = (lane >> 4) * 4, f = ft * 16 + c;
        float* hout = ws + (side ? hout_p : hout_g);
#pragma unroll
        for (int j = 0; j < 4; ++j) {
            float hv = fmaxf(uc[j], 0.f);
            int lr = lr0 + rq + j;
            hout[(size_t)lr * 64 + f] = hv;
            store_hfrag(ws, fout, side, lr, f, hv);
        }
    }
}

// ---------------- K5: partial column sums of final h (64 blocks) ----------------
__global__ __launch_bounds__(256) void k_hsum(float* __restrict__ ws) {
    __shared__ float red[4][NF];
    int bid = blockIdx.x;               // side*32 + b*8 + slab
    int side = bid >> 5, b = (bid >> 3) & 3, slab = bid & 7;
    int t = threadIdx.x, f = t & 63, rr = t >> 6;
    const float* h = ws + (side ? OFF_HB_P : OFF_HB_G)
                     + ((size_t)b * 512 + slab * 64) * 64;
    float s = 0.f;
#pragma unroll
    for (int r = 0; r < 16; ++r) s += h[(size_t)(rr + r * 4) * 64 + f];
    red[rr][f] = s;
    __syncthreads();
    if (rr == 0)
        ws[OFF_HPART + bid * 64 + f] = red[0][f] + red[1][f] + red[2][f] + red[3][f];
}

// ---------------- K6: fused pool + readout. 8 blocks x 256 ----------------
__global__ __launch_bounds__(256) void k_out(const float* __restrict__ Wpg,
                                             const float* __restrict__ Wpp,
                                             const float* __restrict__ Wro,
                                             const float* __restrict__ bro,
                                             const float* __restrict__ ws,
                                             float* __restrict__ out) {
    __shared__ float hp[128];
    __shared__ float c1s;
    int bid = blockIdx.x;
    int row0 = bid * 256, b = row0 >> 9;
    int t = threadIdx.x;
    if (t < 128) {
        int sd = t >> 6, k = t & 63;
        const float* hp8 = ws + OFF_HPART + (size_t)((sd * 4 + b) * 8) * 64 + k;
        float s = 0.f;
#pragma unroll
        for (int s8 = 0; s8 < 8; ++s8) s += hp8[s8 * 64];
        hp[t] = s;
    }
    __syncthreads();
    if (t < 64) {
        float vg = 0.f, vp = 0.f;
#pragma unroll 4
        for (int k = 0; k < 64; ++k) {
            vg += (hp[k] * (1.f / 512.f)) * Wpg[k * 64 + t];
            vp += (hp[64 + k] * (1.f / 512.f)) * Wpp[k * 64 + t];
        }
        float hv = fmaxf(vg + vp, 0.f);
        float c = wave_sum(hv * Wro[t]);
        if (t == 0) c1s = c + bro[0];
    }
    __syncthreads();
    int idx = row0 + t;
    const float4* hrow = (const float4*)(ws + OFF_HB_G + (size_t)idx * 64);
    float s = 0.f;
#pragma unroll
    for (int k4 = 0; k4 < 16; ++k4) {
        float4 h4 = hrow[k4];
        s += h4.x * Wro[64 + k4 * 4 + 0];
        s += h4.y * Wro[64 + k4 * 4 + 1];
        s += h4.z * Wro[64 + k4 * 4 + 2];
        s += h4.w * Wro[64 + k4 * 4 + 3];
    }
    out[idx] = c1s + s;
}

extern "C" void kernel_launch(void* const* d_in, const int* in_sizes, int n_in,
                              void* d_out, int out_size, void* d_ws, size_t ws_size,
                              hipStream_t stream) {
    const float* obs   = (const float*)d_in[0];
    const float* Wi_g  = (const float*)d_in[1];
    const float* Wi_p  = (const float*)d_in[2];
    const float* Wee_g = (const float*)d_in[3];
    const float* Wef_g = (const float*)d_in[4];
    const float* Wee_p = (const float*)d_in[5];
    const float* Wef_p = (const float*)d_in[6];
    const float* Wm_g  = (const float*)d_in[7];
    const float* Wu_g  = (const float*)d_in[8];
    const float* Wm_p  = (const float*)d_in[9];
    const float* Wu_p  = (const float*)d_in[10];
    const float* Wpg   = (const float*)d_in[11];
    const float* Wpp   = (const float*)d_in[12];
    const float* Wro   = (const float*)d_in[13];
    const float* bro   = (const float*)d_in[14];
    float* ws  = (float*)d_ws;
    float* out = (float*)d_out;

    k_wpack<<<48, 256, 0, stream>>>(ws, Wm_g, Wu_g, Wm_p, Wu_p);
    k_prep<<<dim3(64, 4), 256, 0, stream>>>(obs, ws);
    k_norm<<<17, 256, 0, stream>>>(ws, Wee_g, Wef_g, Wee_p, Wef_p);
    k_initpack<<<256, 256, 0, stream>>>(obs, ws, Wi_g, Wi_p, Wef_g, Wef_p);

    k_layer<<<256, 256, 0, stream>>>(ws, 0, OFF_HA_G, OFF_HA_P, OFF_HB_G, OFF_HB_P,
                                     OFF_HFA, OFF_HFB);
    k_layer<<<256, 256, 0, stream>>>(ws, 1, OFF_HB_G, OFF_HB_P, OFF_HA_G, OFF_HA_P,
                                     OFF_HFB, OFF_HFA);
    k_layer<<<256, 256, 0, stream>>>(ws, 2, OFF_HA_G, OFF_HA_P, OFF_HB_G, OFF_HB_P,
                                     OFF_HFA, OFF_HFB);

    k_hsum<<<64, 256, 0, stream>>>(ws);
    k_out<<<8, 256, 0, stream>>>(Wpg, Wpp, Wro, bro, ws, out);
}